// Round 17
// baseline (487.343 us; speedup 1.0000x reference)
//
#include <hip/hip_runtime.h>
#include <math.h>

#define BG   128            // graphs
#define NPER 1024           // nodes per graph, level 0
#define HDIM 128            // hidden
#define NEDGE (BG * NPER * 8)
#define NMAX (BG * NPER)    // 131072
#define EPG  (NEDGE / BG)   // 8192 edges per graph (contiguous slice!)
#define CAP  48             // per-node edge capacity (Poisson(8) tail ~1e-15)
#define PRE  16             // packed-meta entries per node (P(deg>16) ~ 0.4%)
#define CROWS 64            // conv tile rows

typedef float v2f __attribute__((ext_vector_type(2)));

static __device__ __forceinline__ v2f pkfma(v2f a, v2f b, v2f c) {
#if __has_builtin(__builtin_elementwise_fma)
  return __builtin_elementwise_fma(a, b, c);
#else
  v2f r; r.x = fmaf(a.x, b.x, c.x); r.y = fmaf(a.y, b.y, c.y); return r;
#endif
}

// ---------------------------------------------------------------------------
// L0 in-degree count from the input edge list (cnt pre-zeroed) + zero cursor
// ---------------------------------------------------------------------------

__global__ __launch_bounds__(256) void count_kernel(
    const int* __restrict__ ec, int* __restrict__ cnt,
    int* __restrict__ cursor, int n0) {
  int e = blockIdx.x * 256 + threadIdx.x;
  if (e < n0) cursor[e] = 0;
  atomicAdd(&cnt[ec[e]], 1);
}

// ---------------------------------------------------------------------------
// L0 fill: packed per-node meta (graph-LOCAL src, coef); overflow to ext.
// ---------------------------------------------------------------------------

__global__ __launch_bounds__(256) void fill_kernel(
    const int* __restrict__ cr, const int* __restrict__ cc,
    const int* __restrict__ cnt, int* __restrict__ cursor,
    int2* __restrict__ meta16, int* __restrict__ srcext,
    float* __restrict__ cfext, int mask) {
  int e = blockIdx.x * 256 + threadIdx.x;
  int c = cc[e];
  if (c >= 0) {
    int r = cr[e];
    int pos = atomicAdd(&cursor[c], 1);
    float cf = rsqrtf((float)cnt[r] + 1.0f) * rsqrtf((float)cnt[c] + 1.0f);
    int rl = r & mask;                  // graph-local row index
    if (pos < PRE) {
      meta16[(size_t)c * PRE + pos] = make_int2(rl, __float_as_int(cf));
    } else if (pos < CAP) {
      srcext[(size_t)c * CAP + pos] = rl;
      cfext[(size_t)c * CAP + pos] = cf;
    }
  }
}

extern __shared__ float ldsbuf[];

// ---------------------------------------------------------------------------
// agg (L0): 16-channel chunks -> LDS 68 KB -> 2 blocks/CU so one block's
// DS-bound gather overlaps the other's HBM-bound staging (round-16 analysis:
// 132 KB/1-block version had zero overlap across its post-staging barrier).
// Disjoint channel slices: total HBM traffic unchanged. float2 lanes.
// ---------------------------------------------------------------------------

__global__ __launch_bounds__(1024) void agg_lds8_kernel(
    const float* __restrict__ x, float* __restrict__ z,
    const int2* __restrict__ meta16, const int* __restrict__ srcext,
    const float* __restrict__ cfext, const int* __restrict__ deg,
    int npg) {
  float* sX = ldsbuf;                          // [npg][16]
  float* sDinv = sX + npg * 16;                // [npg]
  int g = blockIdx.x >> 3;
  int chunk = blockIdx.x & 7;
  int t = threadIdx.x;
  int base = g * npg;

  const float2* x2 = (const float2*)x;
  float2* sX2 = (float2*)sX;
  for (int i = t; i < npg * 8; i += 1024) {
    int r = i >> 3, l8 = i & 7;
    sX2[i] = x2[(size_t)(base + r) * 64 + chunk * 8 + l8];
  }
  for (int i = t; i < npg; i += 1024)
    sDinv[i] = rsqrtf((float)deg[base + i] + 1.0f);
  __syncthreads();

  int dl = t >> 3, l = t & 7;                  // dst-local slot, lane 0..7
  int base8 = (t & 63) & 56;                   // 8-lane group base within wave
  const int4* m4 = (const int4*)meta16;
  for (int dst = dl; dst < npg; dst += 128) {
    int node = base + dst;
    int4 mq = m4[(size_t)node * 8 + l];        // edges 2l, 2l+1 (coalesced)
    int d = deg[node];
    if (d > CAP) d = CAP;
    float dc = sDinv[dst];
    float s0 = dc * dc;
    float2 row = sX2[dst * 8 + l];
    float2 a0 = make_float2(row.x * s0, row.y * s0);
    float2 a1 = make_float2(0.f, 0.f);
    int dp = d < PRE ? d : PRE;
    int e = 0;
    for (; e + 1 < dp; e += 2) {
      int sl = base8 + (e >> 1);
      int si0 = __shfl(mq.x, sl);
      int si1 = __shfl(mq.z, sl);
      float c0 = __int_as_float(__shfl(mq.y, sl));
      float c1 = __int_as_float(__shfl(mq.w, sl));
      float2 v0 = sX2[si0 * 8 + l];
      float2 v1 = sX2[si1 * 8 + l];
      a0.x = fmaf(v0.x, c0, a0.x); a0.y = fmaf(v0.y, c0, a0.y);
      a1.x = fmaf(v1.x, c1, a1.x); a1.y = fmaf(v1.y, c1, a1.y);
    }
    if (e < dp) {
      int sl = base8 + (e >> 1);
      int si0 = __shfl(mq.x, sl);
      float c0 = __int_as_float(__shfl(mq.y, sl));
      float2 v0 = sX2[si0 * 8 + l];
      a0.x = fmaf(v0.x, c0, a0.x); a0.y = fmaf(v0.y, c0, a0.y);
    }
    for (int e2 = PRE; e2 < d; ++e2) {         // rare overflow (deg > 16)
      int rl = srcext[(size_t)node * CAP + e2];
      float cf = cfext[(size_t)node * CAP + e2];
      float2 v0 = sX2[rl * 8 + l];
      a0.x = fmaf(v0.x, cf, a0.x); a0.y = fmaf(v0.y, cf, a0.y);
    }
    ((float2*)z)[(size_t)node * 64 + chunk * 8 + l] =
        make_float2(a0.x + a1.x, a0.y + a1.y);
  }
}

// ---------------------------------------------------------------------------
// agg (L1/L2): 32-channel chunks, float4 lanes (round-11 design; these
// layers already fit >=2 blocks/CU)
// ---------------------------------------------------------------------------

__global__ __launch_bounds__(1024) void agg_lds_kernel(
    const float* __restrict__ x, float* __restrict__ z,
    const int2* __restrict__ meta16, const int* __restrict__ srcext,
    const float* __restrict__ cfext, const int* __restrict__ deg,
    int npg) {
  float* sX = ldsbuf;                          // [npg][32]
  float* sDinv = sX + npg * 32;                // [npg]
  int g = blockIdx.x >> 2;
  int chunk = blockIdx.x & 3;
  int t = threadIdx.x;
  int base = g * npg;

  const float4* x4 = (const float4*)x;
  float4* sX4 = (float4*)sX;
  for (int i = t; i < npg * 8; i += 1024) {
    int r = i >> 3, l8 = i & 7;
    sX4[i] = x4[(size_t)(base + r) * 32 + chunk * 8 + l8];
  }
  for (int i = t; i < npg; i += 1024)
    sDinv[i] = rsqrtf((float)deg[base + i] + 1.0f);
  __syncthreads();

  int dl = t >> 3, l = t & 7;                  // dst-local slot, lane 0..7
  int base8 = (t & 63) & 56;                   // 8-lane group base within wave
  const int4* m4 = (const int4*)meta16;
  for (int dst = dl; dst < npg; dst += 128) {
    int node = base + dst;
    int4 mq = m4[(size_t)node * 8 + l];        // edges 2l, 2l+1 (coalesced)
    int d = deg[node];
    if (d > CAP) d = CAP;
    float dc = sDinv[dst];
    float s0 = dc * dc;
    float4 row = sX4[dst * 8 + l];
    float4 a0 = make_float4(row.x * s0, row.y * s0, row.z * s0, row.w * s0);
    float4 a1 = make_float4(0.f, 0.f, 0.f, 0.f);
    int dp = d < PRE ? d : PRE;
    int e = 0;
    for (; e + 1 < dp; e += 2) {
      int sl = base8 + (e >> 1);
      int si0 = __shfl(mq.x, sl);
      int si1 = __shfl(mq.z, sl);
      float c0 = __int_as_float(__shfl(mq.y, sl));
      float c1 = __int_as_float(__shfl(mq.w, sl));
      float4 v0 = sX4[si0 * 8 + l];
      float4 v1 = sX4[si1 * 8 + l];
      a0.x = fmaf(v0.x, c0, a0.x); a0.y = fmaf(v0.y, c0, a0.y);
      a0.z = fmaf(v0.z, c0, a0.z); a0.w = fmaf(v0.w, c0, a0.w);
      a1.x = fmaf(v1.x, c1, a1.x); a1.y = fmaf(v1.y, c1, a1.y);
      a1.z = fmaf(v1.z, c1, a1.z); a1.w = fmaf(v1.w, c1, a1.w);
    }
    if (e < dp) {
      int sl = base8 + (e >> 1);
      int si0 = __shfl(mq.x, sl);
      float c0 = __int_as_float(__shfl(mq.y, sl));
      float4 v0 = sX4[si0 * 8 + l];
      a0.x = fmaf(v0.x, c0, a0.x); a0.y = fmaf(v0.y, c0, a0.y);
      a0.z = fmaf(v0.z, c0, a0.z); a0.w = fmaf(v0.w, c0, a0.w);
    }
    for (int e2 = PRE; e2 < d; ++e2) {         // rare overflow (deg > 16)
      int rl = srcext[(size_t)node * CAP + e2];
      float cf = cfext[(size_t)node * CAP + e2];
      float4 v0 = sX4[rl * 8 + l];
      a0.x = fmaf(v0.x, cf, a0.x); a0.y = fmaf(v0.y, cf, a0.y);
      a0.z = fmaf(v0.z, cf, a0.z); a0.w = fmaf(v0.w, cf, a0.w);
    }
    float4 o = make_float4(a0.x + a1.x, a0.y + a1.y, a0.z + a1.z, a0.w + a1.w);
    ((float4*)z)[(size_t)node * 32 + chunk * 8 + l] = o;
  }
}

// ---------------------------------------------------------------------------
// conv: h = relu(z @ W + b) in-place on zh; score = h . p.
// 64x128 tile, block 256 — mapped optimum. W streams L1/L2 with a 2-STAGE
// pipeline (k4,k4+1 in regs, k4+2 loading): W loads are L1-miss streams
// (~200 cyc); 1-deep prefetch left VALUBusy at 54% (round-16).
// ---------------------------------------------------------------------------

__global__ __launch_bounds__(256) void conv_kernel(
    float* __restrict__ zh, const float* __restrict__ W,
    const float* __restrict__ bias, const float* __restrict__ p,
    float* __restrict__ score) {
  __shared__ float sZ[CROWS * HDIM];           // 32 KB
  int tid = threadIdx.x;
  size_t base = (size_t)blockIdx.x * CROWS * HDIM;
  float4* sZ4 = (float4*)sZ;
  const float4* g4 = (const float4*)(zh + base);
  #pragma unroll
  for (int i = 0; i < 8; ++i) sZ4[i * 256 + tid] = g4[i * 256 + tid];
  __syncthreads();

  int col_t = tid & 31;
  int row_t = tid >> 5;
  int r0 = row_t * 8;
  const float4* W4 = (const float4*)W;

  v2f accA[8], accB[8];
  #pragma unroll
  for (int r = 0; r < 8; ++r) {
    accA[r] = (v2f)(0.f);
    accB[r] = (v2f)(0.f);
  }

  float4 wa0 = W4[0 * 32 + col_t];
  float4 wa1 = W4[1 * 32 + col_t];
  float4 wa2 = W4[2 * 32 + col_t];
  float4 wa3 = W4[3 * 32 + col_t];
  float4 wb0 = W4[4 * 32 + col_t];
  float4 wb1 = W4[5 * 32 + col_t];
  float4 wb2 = W4[6 * 32 + col_t];
  float4 wb3 = W4[7 * 32 + col_t];

  for (int k4 = 0; k4 < 32; ++k4) {
    int kn = k4 + 2;
    if (kn > 31) kn = 31;                      // branchless: redundant tail load
    float4 nw0 = W4[(kn * 4 + 0) * 32 + col_t];
    float4 nw1 = W4[(kn * 4 + 1) * 32 + col_t];
    float4 nw2 = W4[(kn * 4 + 2) * 32 + col_t];
    float4 nw3 = W4[(kn * 4 + 3) * 32 + col_t];
    v2f w0a = {wa0.x, wa0.y}, w0b = {wa0.z, wa0.w};
    v2f w1a = {wa1.x, wa1.y}, w1b = {wa1.z, wa1.w};
    v2f w2a = {wa2.x, wa2.y}, w2b = {wa2.z, wa2.w};
    v2f w3a = {wa3.x, wa3.y}, w3b = {wa3.z, wa3.w};
    #pragma unroll
    for (int r = 0; r < 8; ++r) {
      float4 zr = sZ4[(r0 + r) * 32 + k4];
      v2f zx = {zr.x, zr.x};
      v2f zy = {zr.y, zr.y};
      v2f zz = {zr.z, zr.z};
      v2f zw = {zr.w, zr.w};
      accA[r] = pkfma(zx, w0a, accA[r]);
      accB[r] = pkfma(zx, w0b, accB[r]);
      accA[r] = pkfma(zy, w1a, accA[r]);
      accB[r] = pkfma(zy, w1b, accB[r]);
      accA[r] = pkfma(zz, w2a, accA[r]);
      accB[r] = pkfma(zz, w2b, accB[r]);
      accA[r] = pkfma(zw, w3a, accA[r]);
      accB[r] = pkfma(zw, w3b, accB[r]);
    }
    wa0 = wb0; wa1 = wb1; wa2 = wb2; wa3 = wb3;
    wb0 = nw0; wb1 = nw1; wb2 = nw2; wb3 = nw3;
  }

  float4 bv = ((const float4*)bias)[col_t];
  float4 pv = ((const float4*)p)[col_t];
  float4* out4 = (float4*)(zh + base);
  #pragma unroll
  for (int r = 0; r < 8; ++r) {
    float hx = fmaxf(accA[r].x + bv.x, 0.f);
    float hy = fmaxf(accA[r].y + bv.y, 0.f);
    float hz = fmaxf(accB[r].x + bv.z, 0.f);
    float hw = fmaxf(accB[r].y + bv.w, 0.f);
    float part = hx * pv.x + hy * pv.y + hz * pv.z + hw * pv.w;
    #pragma unroll
    for (int sft = 1; sft < 32; sft <<= 1) part += __shfl_xor(part, sft);
    out4[(r0 + r) * 32 + col_t] = make_float4(hx, hy, hz, hw);
    if (col_t == 0) score[blockIdx.x * CROWS + r0 + r] = part;
  }
}

// ---------------------------------------------------------------------------
// MEGA: per-graph block (P threads) — sort + pool/readout + relabel +
// next-layer count/fill all via LDS (edges never cross graphs). L==2 also
// emits the final output. (Round-16 design, unchanged.)
// ---------------------------------------------------------------------------

__global__ __launch_bounds__(1024) void topk_mega_kernel(
    const float* __restrict__ score, const float* __restrict__ p,
    const float* __restrict__ h, float* __restrict__ xo,
    const int* __restrict__ in_r, const int* __restrict__ in_c,
    int* __restrict__ out_r, int* __restrict__ out_c,
    int2* __restrict__ meta16, int* __restrict__ srcext,
    float* __restrict__ cfext, int* __restrict__ cnt,
    float* __restrict__ acc, float* __restrict__ outf,
    int P, int K, int L) {
  __shared__ float sv[1024];
  __shared__ int si[1024];
  __shared__ int snew[1024];
  __shared__ int scnt[512];
  __shared__ int scur[512];
  __shared__ float s_pn;
  __shared__ float4 smx[32][32], ssm[32][32];
  int g = blockIdx.x;
  int t = threadIdx.x;

  if (L < 2 && t < 512) { scnt[t] = 0; scur[t] = 0; }
  snew[t] = -1;
  if (t < 128) { float v = p[t]; sv[t] = v * v; }
  __syncthreads();
  for (int off = 64; off; off >>= 1) {
    if (t < off) sv[t] += sv[t + off];
    __syncthreads();
  }
  if (t == 0) s_pn = sqrtf(sv[0]);
  __syncthreads();
  float pn = s_pn;

  sv[t] = score[(size_t)g * P + t];
  si[t] = t;
  for (int size = 2; size <= P; size <<= 1) {
    for (int stride = size >> 1; stride; stride >>= 1) {
      __syncthreads();
      int j = t ^ stride;
      if (j > t) {
        float a = sv[t], b = sv[j];
        int ia = si[t], ib = si[j];
        bool tFirst = (a > b) || (a == b && ia < ib);
        bool up = ((t & size) == 0);
        if (up ? !tFirst : tFirst) {
          sv[t] = b; sv[j] = a;
          si[t] = ib; si[j] = ia;
        }
      }
    }
  }
  __syncthreads();
  if (t < K) {
    snew[si[t]] = t;                           // graph-LOCAL new id
    sv[t] = tanhf(sv[t] / pn);                 // sv now holds the scale
  }
  __syncthreads();

  // ---- gather + readout: group = 32 lanes, 16 rows per group ----
  int lane = t & 31, grp = t >> 5;             // ngrp = P/32; K/ngrp == 16
  const float4* h4 = (const float4*)h;
  float4* xo4 = (float4*)xo;
  size_t hbase = (size_t)g * P * 32;
  float4 mx = make_float4(-INFINITY, -INFINITY, -INFINITY, -INFINITY);
  float4 sm = make_float4(0.f, 0.f, 0.f, 0.f);
  #pragma unroll
  for (int i = 0; i < 16; ++i) {
    int j = grp * 16 + i;
    float th = sv[j];
    float4 v = h4[hbase + (size_t)si[j] * 32 + lane];
    v.x *= th; v.y *= th; v.z *= th; v.w *= th;
    xo4[((size_t)g * K + j) * 32 + lane] = v;
    mx.x = fmaxf(mx.x, v.x); mx.y = fmaxf(mx.y, v.y);
    mx.z = fmaxf(mx.z, v.z); mx.w = fmaxf(mx.w, v.w);
    sm.x += v.x; sm.y += v.y; sm.z += v.z; sm.w += v.w;
  }
  smx[grp][lane] = mx;
  ssm[grp][lane] = sm;
  __syncthreads();
  int ngrp = P >> 5;
  if (grp == 0) {
    for (int s2 = 1; s2 < ngrp; ++s2) {
      float4 m2 = smx[s2][lane], s3 = ssm[s2][lane];
      mx.x = fmaxf(mx.x, m2.x); mx.y = fmaxf(mx.y, m2.y);
      mx.z = fmaxf(mx.z, m2.z); mx.w = fmaxf(mx.w, m2.w);
      sm.x += s3.x; sm.y += s3.y; sm.z += s3.z; sm.w += s3.w;
    }
    int c0 = lane * 4;
    if (L < 2) {
      float* amax = acc + (size_t)L * BG * 256 + (size_t)g * 256;
      float* asum = amax + 128;
      amax[c0 + 0] = mx.x; amax[c0 + 1] = mx.y;
      amax[c0 + 2] = mx.z; amax[c0 + 3] = mx.w;
      asum[c0 + 0] = sm.x; asum[c0 + 1] = sm.y;
      asum[c0 + 2] = sm.z; asum[c0 + 3] = sm.w;
    } else {                                   // stash own readout in sv
      sv[c0 + 0] = mx.x; sv[c0 + 1] = mx.y;
      sv[c0 + 2] = mx.z; sv[c0 + 3] = mx.w;
      sv[128 + c0 + 0] = sm.x; sv[128 + c0 + 1] = sm.y;
      sv[128 + c0 + 2] = sm.z; sv[128 + c0 + 3] = sm.w;
    }
  }

  if (L == 2) {                                // fold final combine in
    __syncthreads();
    float v;
    const float* a0 = acc + (size_t)g * 256;
    const float* a1 = acc + (size_t)BG * 256 + (size_t)g * 256;
    if (t < 128) {
      v = a0[t] + a1[t] + sv[t];
    } else {
      v = a0[t] * (1.f / 512.f) + a1[t] * (1.f / 256.f) + sv[t] * (1.f / 128.f);
    }
    outf[g * 256 + t] = v;
    return;
  }

  // ---- relabel this graph's edge slice (register-cached) + LDS count ----
  int ept = EPG / P;                           // 8 (P=1024) or 16 (P=512)
  int ebase = g * EPG;
  int er[16], ecl[16];
  #pragma unroll
  for (int i = 0; i < 16; ++i) {
    er[i] = -1; ecl[i] = -1;
    if (i < ept) {
      int e = ebase + i * P + t;               // coalesced
      int r = in_r[e];
      int nr = -1, nc = -1;
      if (r >= 0) {
        nr = snew[r & (P - 1)];
        nc = snew[in_c[e] & (P - 1)];
      }
      bool ok = (nr >= 0) && (nc >= 0);
      out_r[e] = ok ? g * K + nr : -1;
      out_c[e] = ok ? g * K + nc : -1;
      if (ok) {
        er[i] = nr; ecl[i] = nc;
        atomicAdd(&scnt[nc], 1);
      }
    }
  }
  __syncthreads();                             // scnt complete

  // ---- fill next layer's meta (LDS cursor, cnt from LDS) ----
  #pragma unroll
  for (int i = 0; i < 16; ++i) {
    if (er[i] >= 0) {
      int nc = ecl[i];
      int pos = atomicAdd(&scur[nc], 1);
      float cf = rsqrtf((float)scnt[er[i]] + 1.0f) *
                 rsqrtf((float)scnt[nc] + 1.0f);
      size_t gnode = (size_t)g * K + nc;
      if (pos < PRE) {
        meta16[gnode * PRE + pos] = make_int2(er[i], __float_as_int(cf));
      } else if (pos < CAP) {
        srcext[gnode * CAP + pos] = er[i];
        cfext[gnode * CAP + pos] = cf;
      }
    }
  }
  if (t < K) cnt[g * K + t] = scnt[t];         // deg for next agg (coalesced)
}

// ---------------------------------------------------------------------------
// launch
// ---------------------------------------------------------------------------

extern "C" void kernel_launch(void* const* d_in, const int* in_sizes, int n_in,
                              void* d_out, int out_size, void* d_ws, size_t ws_size,
                              hipStream_t stream) {
  const float* x0 = (const float*)d_in[0];
  const int* erow = (const int*)d_in[1];
  const int* ecol = (const int*)d_in[2];
  const float* Wm[3] = {(const float*)d_in[3], (const float*)d_in[6], (const float*)d_in[9]};
  const float* bm[3] = {(const float*)d_in[4], (const float*)d_in[7], (const float*)d_in[10]};
  const float* pm[3] = {(const float*)d_in[5], (const float*)d_in[8], (const float*)d_in[11]};

  char* w = (char*)d_ws;
  size_t off = 0;
  auto alloc = [&](size_t bytes) -> void* {
    void* ptr = w + off;
    off = (off + bytes + 255) & ~(size_t)255;
    return ptr;
  };
  int* cur_row = (int*)alloc((size_t)NEDGE * 4);
  int* cur_col = (int*)alloc((size_t)NEDGE * 4);
  int2* meta16 = (int2*)alloc((size_t)NMAX * PRE * 8);
  int* srcext  = (int*)alloc((size_t)NMAX * CAP * 4);
  float* cfext = (float*)alloc((size_t)NMAX * CAP * 4);
  int* cnt     = (int*)alloc((size_t)NMAX * 4);
  int* cursor  = (int*)alloc((size_t)NMAX * 4);
  float* score = (float*)alloc((size_t)NMAX * 4);
  float* acc   = (float*)alloc((size_t)2 * BG * 256 * 4);
  float* zh    = (float*)alloc((size_t)NMAX * HDIM * 4);
  float* x1    = (float*)alloc((size_t)BG * 512 * HDIM * 4);
  float* x2    = (float*)alloc((size_t)BG * 256 * HDIM * 4);
  float* x3    = (float*)alloc((size_t)BG * 128 * HDIM * 4);

  // allow >64 KB dynamic LDS for the agg kernels
  hipFuncSetAttribute((const void*)agg_lds_kernel,
                      hipFuncAttributeMaxDynamicSharedMemorySize, 152 * 1024);
  hipFuncSetAttribute((const void*)agg_lds8_kernel,
                      hipFuncAttributeMaxDynamicSharedMemorySize, 152 * 1024);

  hipMemsetAsync(cnt, 0, (size_t)NMAX * 4, stream);
  count_kernel<<<NEDGE / 256, 256, 0, stream>>>(ecol, cnt, cursor, NMAX);
  fill_kernel<<<NEDGE / 256, 256, 0, stream>>>(erow, ecol, cnt, cursor,
                                               meta16, srcext, cfext, NPER - 1);

  const float* xin = x0;
  float* xout[3] = {x1, x2, x3};
  int Ps[3] = {1024, 512, 256};

  for (int L = 0; L < 3; ++L) {
    int P = Ps[L];
    int K = P >> 1;
    int n = BG * P;
    const int* in_r = (L == 0) ? erow : cur_row;
    const int* in_c = (L == 0) ? ecol : cur_col;

    if (L == 0) {
      size_t ldsBytes = (size_t)(P * 17) * 4;          // 68 KB -> 2 blocks/CU
      agg_lds8_kernel<<<BG * 8, 1024, ldsBytes, stream>>>(
          xin, zh, meta16, srcext, cfext, cnt, P);
    } else {
      size_t ldsBytes = (size_t)(P * 33) * 4;
      agg_lds_kernel<<<BG * 4, 1024, ldsBytes, stream>>>(
          xin, zh, meta16, srcext, cfext, cnt, P);
    }
    conv_kernel<<<n / CROWS, 256, 0, stream>>>(zh, Wm[L], bm[L], pm[L], score);
    topk_mega_kernel<<<BG, P, 0, stream>>>(
        score, pm[L], zh, xout[L], in_r, in_c, cur_row, cur_col,
        meta16, srcext, cfext, cnt, acc, (float*)d_out, P, K, L);
    xin = xout[L];
  }
}

// Round 18
// 417.560 us; speedup vs baseline: 1.1671x; 1.1671x over previous
//
#include <hip/hip_runtime.h>
#include <math.h>

#define BG   128            // graphs
#define NPER 1024           // nodes per graph, level 0
#define HDIM 128            // hidden
#define NEDGE (BG * NPER * 8)
#define NMAX (BG * NPER)    // 131072
#define EPG  (NEDGE / BG)   // 8192 edges per graph (contiguous slice!)
#define CAP  48             // per-node edge capacity (Poisson(8) tail ~1e-15)
#define PRE  16             // packed-meta entries per node (P(deg>16) ~ 0.4%)
#define CROWS 64            // conv tile rows

typedef float v2f __attribute__((ext_vector_type(2)));

static __device__ __forceinline__ v2f pkfma(v2f a, v2f b, v2f c) {
#if __has_builtin(__builtin_elementwise_fma)
  return __builtin_elementwise_fma(a, b, c);
#else
  v2f r; r.x = fmaf(a.x, b.x, c.x); r.y = fmaf(a.y, b.y, c.y); return r;
#endif
}

// ---------------------------------------------------------------------------
// L0 merged count+fill: ONE atomic per edge gives both the slot position and
// (at the end) the degree. Edge coefficients no longer exist — the GCN norm
// is factored as z[c] = dinv[c] * (sum_e xs[src] + xs[c]) with xs = x*dinv,
// so meta holds ONLY graph-local src ids (int, half the old int2 traffic).
// ---------------------------------------------------------------------------

__global__ __launch_bounds__(256) void countfill_kernel(
    const int* __restrict__ cr, const int* __restrict__ cc,
    int* __restrict__ cnt, int* __restrict__ meta8,
    int* __restrict__ srcext, int mask) {
  int e = blockIdx.x * 256 + threadIdx.x;
  int c = cc[e];
  int rl = cr[e] & mask;                       // graph-local row index
  int pos = atomicAdd(&cnt[c], 1);
  if (pos < PRE) {
    meta8[(size_t)c * PRE + pos] = rl;
  } else if (pos < CAP) {
    srcext[(size_t)c * CAP + pos] = rl;
  }
}

extern __shared__ float ldsbuf[];

// ---------------------------------------------------------------------------
// LDS-resident aggregation (round-16 shape, simplified math):
//  block = (graph, 32-ch chunk); stage PRE-SCALED rows xs = x*dinv -> LDS,
//  one barrier, then each 8-lane group walks its dsts: meta = coalesced int2
//  (2 src ids) + __shfl broadcast; per edge ONE ds_read_b128 + 4 adds (no
//  coefficient!); final multiply by dinv[dst].
// ---------------------------------------------------------------------------

__global__ __launch_bounds__(1024) void agg_lds_kernel(
    const float* __restrict__ x, float* __restrict__ z,
    const int* __restrict__ meta8, const int* __restrict__ srcext,
    const int* __restrict__ deg, int npg) {
  float* sX = ldsbuf;                          // [npg][32], pre-scaled
  float* sDinv = sX + npg * 32;                // [npg]
  int g = blockIdx.x >> 2;
  int chunk = blockIdx.x & 3;
  int t = threadIdx.x;
  int base = g * npg;

  const float4* x4 = (const float4*)x;
  float4* sX4 = (float4*)sX;
  for (int i = t; i < npg * 8; i += 1024) {
    int r = i >> 3, l8 = i & 7;
    float dv = rsqrtf((float)deg[base + r] + 1.0f);
    float4 v = x4[(size_t)(base + r) * 32 + chunk * 8 + l8];
    v.x *= dv; v.y *= dv; v.z *= dv; v.w *= dv;
    sX4[i] = v;
  }
  for (int i = t; i < npg; i += 1024)
    sDinv[i] = rsqrtf((float)deg[base + i] + 1.0f);
  __syncthreads();

  int dl = t >> 3, l = t & 7;                  // dst-local slot, lane 0..7
  int base8 = (t & 63) & 56;                   // 8-lane group base within wave
  const int2* m2 = (const int2*)meta8;
  for (int dst = dl; dst < npg; dst += 128) {
    int node = base + dst;
    int2 mq = m2[(size_t)node * 8 + l];        // src ids for edges 2l, 2l+1
    int d = deg[node];
    if (d > CAP) d = CAP;
    float dc = sDinv[dst];
    float4 a0 = sX4[dst * 8 + l];              // self term (xs[c]); *dc later
    float4 a1 = make_float4(0.f, 0.f, 0.f, 0.f);
    int dp = d < PRE ? d : PRE;
    int e = 0;
    for (; e + 1 < dp; e += 2) {
      int sl = base8 + (e >> 1);
      int si0 = __shfl(mq.x, sl);
      int si1 = __shfl(mq.y, sl);
      float4 v0 = sX4[si0 * 8 + l];
      float4 v1 = sX4[si1 * 8 + l];
      a0.x += v0.x; a0.y += v0.y; a0.z += v0.z; a0.w += v0.w;
      a1.x += v1.x; a1.y += v1.y; a1.z += v1.z; a1.w += v1.w;
    }
    if (e < dp) {
      int sl = base8 + (e >> 1);
      int si0 = __shfl(mq.x, sl);
      float4 v0 = sX4[si0 * 8 + l];
      a0.x += v0.x; a0.y += v0.y; a0.z += v0.z; a0.w += v0.w;
    }
    for (int e2 = PRE; e2 < d; ++e2) {         // rare overflow (deg > 16)
      int rl = srcext[(size_t)node * CAP + e2];
      float4 v0 = sX4[rl * 8 + l];
      a0.x += v0.x; a0.y += v0.y; a0.z += v0.z; a0.w += v0.w;
    }
    float4 o = make_float4((a0.x + a1.x) * dc, (a0.y + a1.y) * dc,
                           (a0.z + a1.z) * dc, (a0.w + a1.w) * dc);
    ((float4*)z)[(size_t)node * 32 + chunk * 8 + l] = o;
  }
}

// ---------------------------------------------------------------------------
// conv: h = relu(z @ W + b) in-place on zh; score = h . p.
// 64x128 tile, block 256, 1-STAGE W prefetch — the mapped optimum (R17's
// 2-stage regressed: register rotation cost > prefetch gain; compiler
// scheduling already near-optimal on this loop).
// ---------------------------------------------------------------------------

__global__ __launch_bounds__(256) void conv_kernel(
    float* __restrict__ zh, const float* __restrict__ W,
    const float* __restrict__ bias, const float* __restrict__ p,
    float* __restrict__ score) {
  __shared__ float sZ[CROWS * HDIM];           // 32 KB
  int tid = threadIdx.x;
  size_t base = (size_t)blockIdx.x * CROWS * HDIM;
  float4* sZ4 = (float4*)sZ;
  const float4* g4 = (const float4*)(zh + base);
  #pragma unroll
  for (int i = 0; i < 8; ++i) sZ4[i * 256 + tid] = g4[i * 256 + tid];
  __syncthreads();

  int col_t = tid & 31;
  int row_t = tid >> 5;
  int r0 = row_t * 8;
  const float4* W4 = (const float4*)W;

  v2f accA[8], accB[8];
  #pragma unroll
  for (int r = 0; r < 8; ++r) {
    accA[r] = (v2f)(0.f);
    accB[r] = (v2f)(0.f);
  }

  float4 w0 = W4[0 * 32 + col_t];
  float4 w1 = W4[1 * 32 + col_t];
  float4 w2 = W4[2 * 32 + col_t];
  float4 w3 = W4[3 * 32 + col_t];

  for (int k4 = 0; k4 < 32; ++k4) {
    int kn = k4 + 1;
    if (kn > 31) kn = 31;                      // branchless: redundant last load
    float4 nw0 = W4[(kn * 4 + 0) * 32 + col_t];
    float4 nw1 = W4[(kn * 4 + 1) * 32 + col_t];
    float4 nw2 = W4[(kn * 4 + 2) * 32 + col_t];
    float4 nw3 = W4[(kn * 4 + 3) * 32 + col_t];
    v2f w0a = {w0.x, w0.y}, w0b = {w0.z, w0.w};
    v2f w1a = {w1.x, w1.y}, w1b = {w1.z, w1.w};
    v2f w2a = {w2.x, w2.y}, w2b = {w2.z, w2.w};
    v2f w3a = {w3.x, w3.y}, w3b = {w3.z, w3.w};
    #pragma unroll
    for (int r = 0; r < 8; ++r) {
      float4 zr = sZ4[(r0 + r) * 32 + k4];
      v2f zx = {zr.x, zr.x};
      v2f zy = {zr.y, zr.y};
      v2f zz = {zr.z, zr.z};
      v2f zw = {zr.w, zr.w};
      accA[r] = pkfma(zx, w0a, accA[r]);
      accB[r] = pkfma(zx, w0b, accB[r]);
      accA[r] = pkfma(zy, w1a, accA[r]);
      accB[r] = pkfma(zy, w1b, accB[r]);
      accA[r] = pkfma(zz, w2a, accA[r]);
      accB[r] = pkfma(zz, w2b, accB[r]);
      accA[r] = pkfma(zw, w3a, accA[r]);
      accB[r] = pkfma(zw, w3b, accB[r]);
    }
    w0 = nw0; w1 = nw1; w2 = nw2; w3 = nw3;
  }

  float4 bv = ((const float4*)bias)[col_t];
  float4 pv = ((const float4*)p)[col_t];
  float4* out4 = (float4*)(zh + base);
  #pragma unroll
  for (int r = 0; r < 8; ++r) {
    float hx = fmaxf(accA[r].x + bv.x, 0.f);
    float hy = fmaxf(accA[r].y + bv.y, 0.f);
    float hz = fmaxf(accB[r].x + bv.z, 0.f);
    float hw = fmaxf(accB[r].y + bv.w, 0.f);
    float part = hx * pv.x + hy * pv.y + hz * pv.z + hw * pv.w;
    #pragma unroll
    for (int sft = 1; sft < 32; sft <<= 1) part += __shfl_xor(part, sft);
    out4[(r0 + r) * 32 + col_t] = make_float4(hx, hy, hz, hw);
    if (col_t == 0) score[blockIdx.x * CROWS + r0 + r] = part;
  }
}

// ---------------------------------------------------------------------------
// MEGA: per-graph block (P threads) — sort + pool/readout + relabel + next-
// layer count/fill via LDS. Coefficient-free meta: relabel loop writes meta8
// directly with ONE LDS atomic (slot+count combined); no second fill pass,
// no barrier between count and fill. L==2 also emits the final output.
// ---------------------------------------------------------------------------

__global__ __launch_bounds__(1024) void topk_mega_kernel(
    const float* __restrict__ score, const float* __restrict__ p,
    const float* __restrict__ h, float* __restrict__ xo,
    const int* __restrict__ in_r, const int* __restrict__ in_c,
    int* __restrict__ out_r, int* __restrict__ out_c,
    int* __restrict__ meta8, int* __restrict__ srcext,
    int* __restrict__ cnt, float* __restrict__ acc,
    float* __restrict__ outf, int P, int K, int L) {
  __shared__ float sv[1024];
  __shared__ int si[1024];
  __shared__ int snew[1024];
  __shared__ int scnt[512];
  __shared__ float s_pn;
  __shared__ float4 smx[32][32], ssm[32][32];
  int g = blockIdx.x;
  int t = threadIdx.x;

  if (L < 2 && t < 512) scnt[t] = 0;
  snew[t] = -1;
  if (t < 128) { float v = p[t]; sv[t] = v * v; }
  __syncthreads();
  for (int off = 64; off; off >>= 1) {
    if (t < off) sv[t] += sv[t + off];
    __syncthreads();
  }
  if (t == 0) s_pn = sqrtf(sv[0]);
  __syncthreads();
  float pn = s_pn;

  sv[t] = score[(size_t)g * P + t];
  si[t] = t;
  for (int size = 2; size <= P; size <<= 1) {
    for (int stride = size >> 1; stride; stride >>= 1) {
      __syncthreads();
      int j = t ^ stride;
      if (j > t) {
        float a = sv[t], b = sv[j];
        int ia = si[t], ib = si[j];
        bool tFirst = (a > b) || (a == b && ia < ib);
        bool up = ((t & size) == 0);
        if (up ? !tFirst : tFirst) {
          sv[t] = b; sv[j] = a;
          si[t] = ib; si[j] = ia;
        }
      }
    }
  }
  __syncthreads();
  if (t < K) {
    snew[si[t]] = t;                           // graph-LOCAL new id
    sv[t] = tanhf(sv[t] / pn);                 // sv now holds the scale
  }
  __syncthreads();

  // ---- gather + readout: group = 32 lanes, 16 rows per group ----
  int lane = t & 31, grp = t >> 5;             // ngrp = P/32; K/ngrp == 16
  const float4* h4 = (const float4*)h;
  float4* xo4 = (float4*)xo;
  size_t hbase = (size_t)g * P * 32;
  float4 mx = make_float4(-INFINITY, -INFINITY, -INFINITY, -INFINITY);
  float4 sm = make_float4(0.f, 0.f, 0.f, 0.f);
  #pragma unroll
  for (int i = 0; i < 16; ++i) {
    int j = grp * 16 + i;
    float th = sv[j];
    float4 v = h4[hbase + (size_t)si[j] * 32 + lane];
    v.x *= th; v.y *= th; v.z *= th; v.w *= th;
    xo4[((size_t)g * K + j) * 32 + lane] = v;
    mx.x = fmaxf(mx.x, v.x); mx.y = fmaxf(mx.y, v.y);
    mx.z = fmaxf(mx.z, v.z); mx.w = fmaxf(mx.w, v.w);
    sm.x += v.x; sm.y += v.y; sm.z += v.z; sm.w += v.w;
  }
  smx[grp][lane] = mx;
  ssm[grp][lane] = sm;
  __syncthreads();
  int ngrp = P >> 5;
  if (grp == 0) {
    for (int s2 = 1; s2 < ngrp; ++s2) {
      float4 m2 = smx[s2][lane], s3 = ssm[s2][lane];
      mx.x = fmaxf(mx.x, m2.x); mx.y = fmaxf(mx.y, m2.y);
      mx.z = fmaxf(mx.z, m2.z); mx.w = fmaxf(mx.w, m2.w);
      sm.x += s3.x; sm.y += s3.y; sm.z += s3.z; sm.w += s3.w;
    }
    int c0 = lane * 4;
    if (L < 2) {
      float* amax = acc + (size_t)L * BG * 256 + (size_t)g * 256;
      float* asum = amax + 128;
      amax[c0 + 0] = mx.x; amax[c0 + 1] = mx.y;
      amax[c0 + 2] = mx.z; amax[c0 + 3] = mx.w;
      asum[c0 + 0] = sm.x; asum[c0 + 1] = sm.y;
      asum[c0 + 2] = sm.z; asum[c0 + 3] = sm.w;
    } else {                                   // stash own readout in sv
      sv[c0 + 0] = mx.x; sv[c0 + 1] = mx.y;
      sv[c0 + 2] = mx.z; sv[c0 + 3] = mx.w;
      sv[128 + c0 + 0] = sm.x; sv[128 + c0 + 1] = sm.y;
      sv[128 + c0 + 2] = sm.z; sv[128 + c0 + 3] = sm.w;
    }
  }

  if (L == 2) {                                // fold final combine in
    __syncthreads();
    float v;
    const float* a0 = acc + (size_t)g * 256;
    const float* a1 = acc + (size_t)BG * 256 + (size_t)g * 256;
    if (t < 128) {
      v = a0[t] + a1[t] + sv[t];
    } else {
      v = a0[t] * (1.f / 512.f) + a1[t] * (1.f / 256.f) + sv[t] * (1.f / 128.f);
    }
    outf[g * 256 + t] = v;
    return;
  }

  // ---- relabel + count + fill in ONE pass (single LDS atomic per edge) ----
  int ept = EPG / P;                           // 8 (P=1024) or 16 (P=512)
  int ebase = g * EPG;
  for (int i = 0; i < ept; ++i) {
    int e = ebase + i * P + t;                 // coalesced
    int r = in_r[e];
    int nr = -1, nc = -1;
    if (r >= 0) {
      nr = snew[r & (P - 1)];
      nc = snew[in_c[e] & (P - 1)];
    }
    bool ok = (nr >= 0) && (nc >= 0);
    out_r[e] = ok ? g * K + nr : -1;
    out_c[e] = ok ? g * K + nc : -1;
    if (ok) {
      int pos = atomicAdd(&scnt[nc], 1);
      size_t gnode = (size_t)g * K + nc;
      if (pos < PRE) {
        meta8[gnode * PRE + pos] = nr;
      } else if (pos < CAP) {
        srcext[gnode * CAP + pos] = nr;
      }
    }
  }
  __syncthreads();                             // scnt complete
  if (t < K) cnt[g * K + t] = scnt[t];         // deg for next agg (coalesced)
}

// ---------------------------------------------------------------------------
// launch
// ---------------------------------------------------------------------------

extern "C" void kernel_launch(void* const* d_in, const int* in_sizes, int n_in,
                              void* d_out, int out_size, void* d_ws, size_t ws_size,
                              hipStream_t stream) {
  const float* x0 = (const float*)d_in[0];
  const int* erow = (const int*)d_in[1];
  const int* ecol = (const int*)d_in[2];
  const float* Wm[3] = {(const float*)d_in[3], (const float*)d_in[6], (const float*)d_in[9]};
  const float* bm[3] = {(const float*)d_in[4], (const float*)d_in[7], (const float*)d_in[10]};
  const float* pm[3] = {(const float*)d_in[5], (const float*)d_in[8], (const float*)d_in[11]};

  char* w = (char*)d_ws;
  size_t off = 0;
  auto alloc = [&](size_t bytes) -> void* {
    void* ptr = w + off;
    off = (off + bytes + 255) & ~(size_t)255;
    return ptr;
  };
  int* cur_row = (int*)alloc((size_t)NEDGE * 4);
  int* cur_col = (int*)alloc((size_t)NEDGE * 4);
  int* meta8   = (int*)alloc((size_t)NMAX * PRE * 4);
  int* srcext  = (int*)alloc((size_t)NMAX * CAP * 4);
  int* cnt     = (int*)alloc((size_t)NMAX * 4);
  float* score = (float*)alloc((size_t)NMAX * 4);
  float* acc   = (float*)alloc((size_t)2 * BG * 256 * 4);
  float* zh    = (float*)alloc((size_t)NMAX * HDIM * 4);
  float* x1    = (float*)alloc((size_t)BG * 512 * HDIM * 4);
  float* x2    = (float*)alloc((size_t)BG * 256 * HDIM * 4);
  float* x3    = (float*)alloc((size_t)BG * 128 * HDIM * 4);

  // allow >64 KB dynamic LDS for the agg kernel (L0 needs 132 KB)
  hipFuncSetAttribute((const void*)agg_lds_kernel,
                      hipFuncAttributeMaxDynamicSharedMemorySize, 152 * 1024);

  hipMemsetAsync(cnt, 0, (size_t)NMAX * 4, stream);
  countfill_kernel<<<NEDGE / 256, 256, 0, stream>>>(erow, ecol, cnt, meta8,
                                                    srcext, NPER - 1);

  const float* xin = x0;
  float* xout[3] = {x1, x2, x3};
  int Ps[3] = {1024, 512, 256};

  for (int L = 0; L < 3; ++L) {
    int P = Ps[L];
    int K = P >> 1;
    int n = BG * P;
    const int* in_r = (L == 0) ? erow : cur_row;
    const int* in_c = (L == 0) ? ecol : cur_col;
    size_t ldsBytes = (size_t)(P * 33) * 4;

    agg_lds_kernel<<<BG * 4, 1024, ldsBytes, stream>>>(
        xin, zh, meta8, srcext, cnt, P);
    conv_kernel<<<n / CROWS, 256, 0, stream>>>(zh, Wm[L], bm[L], pm[L], score);
    topk_mega_kernel<<<BG, P, 0, stream>>>(
        score, pm[L], zh, xout[L], in_r, in_c, cur_row, cur_col,
        meta8, srcext, cnt, acc, (float*)d_out, P, K, L);
    xin = xout[L];
  }
}